// Round 12
// baseline (185.653 us; speedup 1.0000x reference)
//
#include <hip/hip_runtime.h>
#include <hip/hip_fp8.h>

#define C_ 512
#define T_ 2048
#define N_TOK 16384
#define K_CB 4096

typedef __attribute__((ext_vector_type(16))) float f32x16;

static __device__ __forceinline__ unsigned char f2fp8(float f) {
    __hip_fp8_e4m3 v(f);                 // OCP e4m3, RNE + saturate
    return (unsigned char)v.__x;
}

typedef const __attribute__((address_space(1))) void* gas_t;
typedef __attribute__((address_space(3))) void* las_t;
static __device__ __forceinline__ void stage16(const void* g, void* l) {
    __builtin_amdgcn_global_load_lds((gas_t)g, (las_t)l, 16, 0, 0);
}

// ---------------- Kernel 1: transpose student (B,C,T)->(N,C) fp8 + per-token partial stats ------
__global__ __launch_bounds__(256) void k1_prep(
    const float* __restrict__ student,   // (B,C,T) fp32
    const int* __restrict__ codes,       // (B,T) int32
    const float* __restrict__ codebook,  // (K,C) fp32
    unsigned char* __restrict__ A8,      // (N,C) fp8 out
    float* __restrict__ xnorm, float* __restrict__ dtg2)
{
    __shared__ float tile[64][65];
    __shared__ int lcodes[64];
    int tid = threadIdx.x;
    int tnum  = blockIdx.x >> 1;
    int chalf = blockIdx.x & 1;
    int b  = tnum >> 5;
    int t0 = (tnum & 31) << 6;
    int cbase = chalf << 8;             // 0 or 256
    int cx = tid & 63;                  // lane
    int q  = tid >> 6;                  // wave
    if (tid < 64) lcodes[tid] = codes[b * T_ + t0 + tid];
    __syncthreads();
    float ax2[16], ad2[16];
#pragma unroll
    for (int p = 0; p < 16; ++p) { ax2[p] = 0.f; ad2[p] = 0.f; }
    for (int c0 = cbase; c0 < cbase + 256; c0 += 64) {
#pragma unroll
        for (int p = 0; p < 16; ++p) {
            int ch = p * 4 + q;
            tile[ch][cx] = student[(size_t)b * (C_ * T_) + (size_t)(c0 + ch) * T_ + t0 + cx];
        }
        __syncthreads();
#pragma unroll
        for (int p = 0; p < 16; ++p) {
            int ty = p * 4 + q;
            float x = tile[cx][ty];
            int n = b * T_ + t0 + ty;
            A8[(size_t)n * C_ + c0 + cx] = f2fp8(x);
            ax2[p] += x * x;
            float cb = codebook[(size_t)lcodes[ty] * C_ + c0 + cx];
            float d = x - cb;
            ad2[p] += d * d;
        }
        __syncthreads();
    }
#pragma unroll
    for (int p = 0; p < 16; ++p) {
        float sx = ax2[p], sd = ad2[p];
#pragma unroll
        for (int m = 1; m < 64; m <<= 1) {
            sx += __shfl_xor(sx, m);
            sd += __shfl_xor(sd, m);
        }
        if (cx == 0) {
            int n = b * T_ + t0 + p * 4 + q;
            atomicAdd(&xnorm[n], sx);
            atomicAdd(&dtg2[n], sd);
        }
    }
}

// ---------------- Kernel 1b: codebook -> FRAGMENT-LINEAR fp8 + norms + init ----------------
// B8f layout: [group g=row>>5][m=k>>4][kh][col=row&31][8B] -> a wave's B-fragment load is
// lane-linear: addr = g*16384 + m*512 + lane*8 (512B contiguous per load).
__global__ __launch_bounds__(256) void k1_cb(
    const float* __restrict__ codebook,
    unsigned char* __restrict__ B8f,
    float* __restrict__ cbnorm,
    float* __restrict__ s_sum,
    unsigned* __restrict__ minpack,
    float* __restrict__ xnorm, float* __restrict__ dtg2,
    float* __restrict__ accum)
{
    int tid = threadIdx.x;
    int gidx = blockIdx.x * 256 + tid;
    if (gidx < N_TOK) {
        s_sum[gidx] = 0.f; minpack[gidx] = 0xFFFFFFFFu;
        xnorm[gidx] = 0.f; dtg2[gidx] = 0.f;
    }
    if (gidx < 8) accum[gidx] = 0.f;
    int lane = tid & 63;
    int w = tid >> 6;
    int row = blockIdx.x * 4 + w;
    const float* src = codebook + (size_t)row * C_ + lane * 8;
    float4 v0 = *(const float4*)(src);
    float4 v1 = *(const float4*)(src + 4);
    float s = v0.x*v0.x + v0.y*v0.y + v0.z*v0.z + v0.w*v0.w
            + v1.x*v1.x + v1.y*v1.y + v1.z*v1.z + v1.w*v1.w;
    unsigned lo = (unsigned)f2fp8(v0.x) | ((unsigned)f2fp8(v0.y) << 8)
                | ((unsigned)f2fp8(v0.z) << 16) | ((unsigned)f2fp8(v0.w) << 24);
    unsigned hi = (unsigned)f2fp8(v1.x) | ((unsigned)f2fp8(v1.y) << 8)
                | ((unsigned)f2fp8(v1.z) << 16) | ((unsigned)f2fp8(v1.w) << 24);
    // this lane's 8B = k-bytes [lane*8, lane*8+8) -> m = lane>>1, kh = lane&1
    size_t off = (size_t)(row >> 5) * 16384 + (size_t)(lane >> 1) * 512
               + (size_t)(lane & 1) * 256 + (size_t)(row & 31) * 8;
    *(uint2*)(B8f + off) = make_uint2(lo, hi);
#pragma unroll
    for (int m = 1; m < 64; m <<= 1) s += __shfl_xor(s, m);
    if (lane == 0) cbnorm[row] = s;
}

// ---------------- Kernel 2: barrier-free fp8 32x32 MFMA: fraglin-A LDS + fraglin-B global ------
// grid = 512 (256 row-strips x 2 col-halves, XCD-chunked); block = 512 (8 waves, 1x8:
// wave = all 64 student rows x its own 32 cb-cols per cc).
// A (64x512 = 32KB) reg-staged once into fragment-linear LDS (conflict-free ds_read_b64);
// B loaded per-cc from fragment-linear GLOBAL (coalesced dwordx2, L2-resident, 32 VGPR strip,
// two 16-reg half-loads). ONE barrier total after staging; main loop has zero barriers,
// zero LDS writes. Swapped mfma(cb, student) -> in-register epilogue + 1 shfl + atomics.
__global__ __launch_bounds__(512, 4) void k2_main(
    const unsigned char* __restrict__ A8,
    const unsigned char* __restrict__ B8f,
    const float* __restrict__ xnorm,
    const float* __restrict__ dtg2,
    const float* __restrict__ cbnorm,
    float* __restrict__ s_sum,
    unsigned* __restrict__ minpack)
{
    __shared__ __align__(16) unsigned char aL[32768];      // A fraglin: [rt2][m32][kh2][lane^m]
    __shared__ __align__(16) float cbL[2048];              // cbnorm for this col-half
    int tid = threadIdx.x;
    int lane = tid & 63;
    int wc = tid >> 6;                   // 0..7: wave owns cols [wc*32, wc*32+32) of each cc
    int l31 = lane & 31;
    int kh = lane >> 5;

    int orig = blockIdx.x;               // 512 = 8 XCD x 64
    int swz = (orig & 7) * 64 + (orig >> 3);
    int strip = swz >> 1;                // 0..255
    int chalf = swz & 1;
    int row0 = strip * 64;
    int cbase = chalf * 2048;

    // ---- stage A once, reg->LDS, fragment-linear with m-XOR lane swizzle (R11-verified) ----
#pragma unroll
    for (int i = 0; i < 4; ++i) {
        int li = i * 512 + tid;
        int R = li >> 5, M = li & 31;
        uint4 v = *(const uint4*)(A8 + (size_t)(row0 + R) * C_ + M * 16);
        char* base = (char*)aL + (R >> 5) * 16384 + M * 512;
        int lx = (R & 31) ^ M;
        *(uint2*)(base + lx * 8)       = make_uint2(v.x, v.y);   // kh = 0
        *(uint2*)(base + 256 + lx * 8) = make_uint2(v.z, v.w);   // kh = 1
    }
    // ---- stage cbnorm half once ----
    stage16((const char*)cbnorm + (size_t)cbase * 4 + tid * 16, (char*)cbL + tid * 16);
    __syncthreads();                     // the ONLY barrier

    int myrow0 = row0 + l31, myrow1 = row0 + 32 + l31;
    float xn0 = xnorm[myrow0], xn1 = xnorm[myrow1];
    float dt0 = sqrtf(dtg2[myrow0]), dt1 = sqrtf(dtg2[myrow1]);
    float sv0 = 0.f, sv1 = 0.f;
    unsigned km0 = 0xFFFFFFFFu, km1 = 0xFFFFFFFFu;

    f32x16 acc0, acc1;                   // rt = 0 / 1
#pragma unroll
    for (int r = 0; r < 16; ++r) { acc0[r] = 0.f; acc1[r] = 0.f; }

    const unsigned char* gB0 = B8f + (size_t)(chalf * 64 + wc) * 16384 + lane * 8;
    int wlc = wc * 32 + 4 * kh;          // lane's col base within a cc (local)

    for (int cc = 0; cc < 8; ++cc) {
        const unsigned char* gB = gB0 + (size_t)cc * (8 * 16384);
        long bReg[16], aF0, aF1;
        // ---- half 0: m = 0..15 ----
#pragma unroll
        for (int m = 0; m < 16; ++m)
            bReg[m] = *(const long*)(gB + m * 512);
#pragma unroll
        for (int m = 0; m < 16; ++m) {
            int ao = m * 512 + ((lane ^ m) * 8);
            aF0 = *(const long*)((const char*)aL + ao);
            aF1 = *(const long*)((const char*)aL + 16384 + ao);
            acc0 = __builtin_amdgcn_mfma_f32_32x32x16_fp8_fp8(bReg[m], aF0, acc0, 0, 0, 0);
            acc1 = __builtin_amdgcn_mfma_f32_32x32x16_fp8_fp8(bReg[m], aF1, acc1, 0, 0, 0);
        }
        // ---- half 1: m = 16..31 (reuse bReg) ----
#pragma unroll
        for (int m = 0; m < 16; ++m)
            bReg[m] = *(const long*)(gB + (16 + m) * 512);
#pragma unroll
        for (int m = 0; m < 16; ++m) {
            int mm = 16 + m;
            int ao = mm * 512 + ((lane ^ mm) * 8);
            aF0 = *(const long*)((const char*)aL + ao);
            aF1 = *(const long*)((const char*)aL + 16384 + ao);
            acc0 = __builtin_amdgcn_mfma_f32_32x32x16_fp8_fp8(bReg[m], aF0, acc0, 0, 0, 0);
            acc1 = __builtin_amdgcn_mfma_f32_32x32x16_fp8_fp8(bReg[m], aF1, acc1, 0, 0, 0);
        }
        // ---- epilogue burst for this cc (waves de-phase naturally: no barriers) ----
        int lc0 = cc * 256 + wlc;
#pragma unroll
        for (int r = 0; r < 16; ++r) {
            int lc = lc0 + (r & 3) + 8 * (r >> 2);
            float cbn = cbL[lc];
            float d0 = sqrtf(fmaxf(fmaf(-2.f, acc0[r], xn0) + cbn, 0.f));
            sv0 += __expf(dt0 - d0);
            km0 = min(km0, (__float_as_uint(d0) & 0xFFFFF000u) | (unsigned)(cbase + lc));
            float d1 = sqrtf(fmaxf(fmaf(-2.f, acc1[r], xn1) + cbn, 0.f));
            sv1 += __expf(dt1 - d1);
            km1 = min(km1, (__float_as_uint(d1) & 0xFFFFF000u) | (unsigned)(cbase + lc));
            acc0[r] = 0.f; acc1[r] = 0.f;
        }
    }

    // merge k-halves (lane vs lane+32: same student rows, disjoint cb-col quads)
    sv0 += __shfl_xor(sv0, 32);
    sv1 += __shfl_xor(sv1, 32);
    km0 = min(km0, (unsigned)__shfl_xor((int)km0, 32));
    km1 = min(km1, (unsigned)__shfl_xor((int)km1, 32));
    if (lane < 32) {
        atomicAdd(&s_sum[myrow0], sv0);
        atomicMin(&minpack[myrow0], km0);
        atomicAdd(&s_sum[myrow1], sv1);
        atomicMin(&minpack[myrow1], km1);
    }
}

// ---------------- Kernel 3a: per-token CE/accuracy/emb-loss/target-dist reduce ----------------
__global__ __launch_bounds__(256) void k3a(
    const float* __restrict__ s_sum,
    const unsigned* __restrict__ minpack,
    const int* __restrict__ codes,
    const float* __restrict__ dtg2,
    float* __restrict__ accum)
{
    __shared__ float w0[4], w1[4], w2[4], w3[4];
    int tid = threadIdx.x;
    int n = blockIdx.x * 256 + tid;
    float ce = logf(s_sum[n]);           // = d_t + lse(-d) = per-token CE
    unsigned pred = minpack[n] & 0xFFFu; // col id in the low 12 bits
    float ok = (pred == (unsigned)codes[n]) ? 1.f : 0.f;
    float sq = dtg2[n];
    float td = sqrtf(sq);
#pragma unroll
    for (int m = 1; m < 64; m <<= 1) {
        ce += __shfl_xor(ce, m);
        ok += __shfl_xor(ok, m);
        sq += __shfl_xor(sq, m);
        td += __shfl_xor(td, m);
    }
    int lane = tid & 63, w = tid >> 6;
    if (lane == 0) { w0[w] = ce; w1[w] = ok; w2[w] = sq; w3[w] = td; }
    __syncthreads();
    if (tid == 0) {
        atomicAdd(&accum[0], w0[0] + w0[1] + w0[2] + w0[3]);
        atomicAdd(&accum[1], w1[0] + w1[1] + w1[2] + w1[3]);
        atomicAdd(&accum[2], w2[0] + w2[1] + w2[2] + w2[3]);
        atomicAdd(&accum[3], w3[0] + w3[1] + w3[2] + w3[3]);
    }
}

// ---------------- Kernel 3b: finalize 5 outputs ----------------
__global__ void k3b(const float* __restrict__ accum, float* __restrict__ out)
{
    if (threadIdx.x == 0 && blockIdx.x == 0) {
        float ce   = accum[0] / (float)N_TOK;
        float accy = accum[1] / (float)N_TOK;
        float emb  = accum[2] / ((float)N_TOK * (float)C_);
        float td   = accum[3] / (float)N_TOK;
        out[0] = emb + ce;   // total_loss (EMB_W=CE_W=1)
        out[1] = emb;        // emb_to_codebook_loss
        out[2] = ce;         // ce_loss
        out[3] = accy;       // token_accuracy
        out[4] = td;         // emb_to_target_dist
    }
}

extern "C" void kernel_launch(void* const* d_in, const int* in_sizes, int n_in,
                              void* d_out, int out_size, void* d_ws, size_t ws_size,
                              hipStream_t stream)
{
    const float* student  = (const float*)d_in[0];
    const int*   codes    = (const int*)d_in[1];
    const float* codebook = (const float*)d_in[2];
    // d_in[3] distance_matrix is unused by the reference.
    float* out = (float*)d_out;

    char* ws = (char*)d_ws;
    unsigned char* A8     = (unsigned char*)(ws);                  // 8 MiB
    unsigned char* B8f    = (unsigned char*)(ws + 8388608);        // 2 MiB (fragment-linear)
    float* xnorm          = (float*)(ws + 10485760);               // 64 KiB
    float* dtg2           = (float*)(ws + 10551296);               // 64 KiB
    float* cbnorm         = (float*)(ws + 10616832);               // 16 KiB
    float* s_sum          = (float*)(ws + 10633216);               // 64 KiB
    unsigned* minpack     = (unsigned*)(ws + 10698752);            // 64 KiB
    float* accum          = (float*)(ws + 10829824);               // 64 B

    // k1_cb zero-inits s_sum/minpack/xnorm/dtg2/accum (stream-ordered before k1_prep's atomics)
    hipLaunchKernelGGL(k1_cb, dim3(1024), dim3(256), 0, stream,
                       codebook, B8f, cbnorm, s_sum, minpack, xnorm, dtg2, accum);
    hipLaunchKernelGGL(k1_prep, dim3(512), dim3(256), 0, stream,
                       student, codes, codebook, A8, xnorm, dtg2);
    hipLaunchKernelGGL(k2_main, dim3(512), dim3(512), 0, stream,
                       A8, B8f, xnorm, dtg2, cbnorm, s_sum, minpack);
    hipLaunchKernelGGL(k3a, dim3(64), dim3(256), 0, stream,
                       s_sum, minpack, codes, dtg2, accum);
    hipLaunchKernelGGL(k3b, dim3(1), dim3(64), 0, stream, accum, out);
}

// Round 13
// 168.464 us; speedup vs baseline: 1.1020x; 1.1020x over previous
//
#include <hip/hip_runtime.h>
#include <hip/hip_fp8.h>

#define C_ 512
#define T_ 2048
#define N_TOK 16384
#define K_CB 4096

typedef __attribute__((ext_vector_type(16))) float f32x16;

static __device__ __forceinline__ unsigned char f2fp8(float f) {
    __hip_fp8_e4m3 v(f);                 // OCP e4m3, RNE + saturate
    return (unsigned char)v.__x;
}

typedef const __attribute__((address_space(1))) void* gas_t;
typedef __attribute__((address_space(3))) void* las_t;
static __device__ __forceinline__ void stage16(const void* g, void* l) {
    __builtin_amdgcn_global_load_lds((gas_t)g, (las_t)l, 16, 0, 0);
}

// ---------------- Kernel 1: transpose student (B,C,T)->(N,C) fp8 + per-token partial stats ------
__global__ __launch_bounds__(256) void k1_prep(
    const float* __restrict__ student,   // (B,C,T) fp32
    const int* __restrict__ codes,       // (B,T) int32
    const float* __restrict__ codebook,  // (K,C) fp32
    unsigned char* __restrict__ A8,      // (N,C) fp8 out
    float* __restrict__ xnorm, float* __restrict__ dtg2)
{
    __shared__ float tile[64][65];
    __shared__ int lcodes[64];
    int tid = threadIdx.x;
    int tnum  = blockIdx.x >> 1;
    int chalf = blockIdx.x & 1;
    int b  = tnum >> 5;
    int t0 = (tnum & 31) << 6;
    int cbase = chalf << 8;             // 0 or 256
    int cx = tid & 63;                  // lane
    int q  = tid >> 6;                  // wave
    if (tid < 64) lcodes[tid] = codes[b * T_ + t0 + tid];
    __syncthreads();
    float ax2[16], ad2[16];
#pragma unroll
    for (int p = 0; p < 16; ++p) { ax2[p] = 0.f; ad2[p] = 0.f; }
    for (int c0 = cbase; c0 < cbase + 256; c0 += 64) {
#pragma unroll
        for (int p = 0; p < 16; ++p) {
            int ch = p * 4 + q;
            tile[ch][cx] = student[(size_t)b * (C_ * T_) + (size_t)(c0 + ch) * T_ + t0 + cx];
        }
        __syncthreads();
#pragma unroll
        for (int p = 0; p < 16; ++p) {
            int ty = p * 4 + q;
            float x = tile[cx][ty];
            int n = b * T_ + t0 + ty;
            A8[(size_t)n * C_ + c0 + cx] = f2fp8(x);
            ax2[p] += x * x;
            float cb = codebook[(size_t)lcodes[ty] * C_ + c0 + cx];
            float d = x - cb;
            ad2[p] += d * d;
        }
        __syncthreads();
    }
#pragma unroll
    for (int p = 0; p < 16; ++p) {
        float sx = ax2[p], sd = ad2[p];
#pragma unroll
        for (int m = 1; m < 64; m <<= 1) {
            sx += __shfl_xor(sx, m);
            sd += __shfl_xor(sd, m);
        }
        if (cx == 0) {
            int n = b * T_ + t0 + p * 4 + q;
            atomicAdd(&xnorm[n], sx);
            atomicAdd(&dtg2[n], sd);
        }
    }
}

// ---------------- Kernel 1b: codebook -> FRAGMENT-LINEAR fp8 + norms + init ----------------
// B8f layout: [g=row>>5][m=k>>4][kh][col=row&31][8B] -> wave B-fragment load is lane-linear:
// addr = g*16384 + m*512 + kh*256 + col*8 (512B contiguous per fragment).
__global__ __launch_bounds__(256) void k1_cb(
    const float* __restrict__ codebook,
    unsigned char* __restrict__ B8f,
    float* __restrict__ cbnorm,
    float* __restrict__ s_sum,
    unsigned* __restrict__ minpack,
    float* __restrict__ xnorm, float* __restrict__ dtg2,
    float* __restrict__ accum)
{
    int tid = threadIdx.x;
    int gidx = blockIdx.x * 256 + tid;
    if (gidx < N_TOK) {
        s_sum[gidx] = 0.f; minpack[gidx] = 0xFFFFFFFFu;
        xnorm[gidx] = 0.f; dtg2[gidx] = 0.f;
    }
    if (gidx < 8) accum[gidx] = 0.f;
    int lane = tid & 63;
    int w = tid >> 6;
    int row = blockIdx.x * 4 + w;
    const float* src = codebook + (size_t)row * C_ + lane * 8;
    float4 v0 = *(const float4*)(src);
    float4 v1 = *(const float4*)(src + 4);
    float s = v0.x*v0.x + v0.y*v0.y + v0.z*v0.z + v0.w*v0.w
            + v1.x*v1.x + v1.y*v1.y + v1.z*v1.z + v1.w*v1.w;
    unsigned lo = (unsigned)f2fp8(v0.x) | ((unsigned)f2fp8(v0.y) << 8)
                | ((unsigned)f2fp8(v0.z) << 16) | ((unsigned)f2fp8(v0.w) << 24);
    unsigned hi = (unsigned)f2fp8(v1.x) | ((unsigned)f2fp8(v1.y) << 8)
                | ((unsigned)f2fp8(v1.z) << 16) | ((unsigned)f2fp8(v1.w) << 24);
    // this lane's 8B = k-bytes [lane*8, lane*8+8) -> m = lane>>1, kh = lane&1
    size_t off = (size_t)(row >> 5) * 16384 + (size_t)(lane >> 1) * 512
               + (size_t)(lane & 1) * 256 + (size_t)(row & 31) * 8;
    *(uint2*)(B8f + off) = make_uint2(lo, hi);
#pragma unroll
    for (int m = 1; m < 64; m <<= 1) s += __shfl_xor(s, m);
    if (lane == 0) cbnorm[row] = s;
}

// ---------------- Kernel 2: barrier-free fp8 32x32 MFMA, fraglin-A LDS + 4-frag streamed B ------
// grid = 512 (256 row-strips x 2 col-halves, XCD-chunked); block = 512 (8 waves, 1x8:
// wave = all 64 student rows x its own 32 cb-cols per cc).
// A (64x512 = 32KB) reg-staged once into fragment-linear LDS (conflict-free ds_read_b64).
// B streamed from fragment-linear GLOBAL in 4-frag chunks (8 named VGPRs current + 8 prefetch
// -- NO register arrays, no spill), coalesced 512B loads, L2-resident.
// ONE barrier total; main loop: zero barriers, zero LDS writes, zero bank conflicts.
__global__ __launch_bounds__(512, 4) void k2_main(
    const unsigned char* __restrict__ A8,
    const unsigned char* __restrict__ B8f,
    const float* __restrict__ xnorm,
    const float* __restrict__ dtg2,
    const float* __restrict__ cbnorm,
    float* __restrict__ s_sum,
    unsigned* __restrict__ minpack)
{
    __shared__ __align__(16) unsigned char aL[32768];      // A fraglin: [rt2][m32][kh2][lane^m]
    __shared__ __align__(16) float cbL[2048];              // cbnorm for this col-half
    int tid = threadIdx.x;
    int lane = tid & 63;
    int wc = tid >> 6;                   // 0..7: wave owns cols [wc*32, wc*32+32) of each cc
    int l31 = lane & 31;
    int kh = lane >> 5;

    int orig = blockIdx.x;               // 512 = 8 XCD x 64
    int swz = (orig & 7) * 64 + (orig >> 3);
    int strip = swz >> 1;                // 0..255
    int chalf = swz & 1;
    int row0 = strip * 64;
    int cbase = chalf * 2048;

    // ---- stage A once, reg->LDS, fragment-linear with m-XOR lane swizzle (R11/R12-verified) ----
#pragma unroll
    for (int i = 0; i < 4; ++i) {
        int li = i * 512 + tid;
        int R = li >> 5, M = li & 31;
        uint4 v = *(const uint4*)(A8 + (size_t)(row0 + R) * C_ + M * 16);
        char* base = (char*)aL + (R >> 5) * 16384 + M * 512;
        int lx = (R & 31) ^ M;
        *(uint2*)(base + lx * 8)       = make_uint2(v.x, v.y);   // kh = 0
        *(uint2*)(base + 256 + lx * 8) = make_uint2(v.z, v.w);   // kh = 1
    }
    // ---- stage cbnorm half once ----
    stage16((const char*)cbnorm + (size_t)cbase * 4 + tid * 16, (char*)cbL + tid * 16);
    __syncthreads();                     // the ONLY barrier

    int myrow0 = row0 + l31, myrow1 = row0 + 32 + l31;
    float xn0 = xnorm[myrow0], xn1 = xnorm[myrow1];
    float dt0 = sqrtf(dtg2[myrow0]), dt1 = sqrtf(dtg2[myrow1]);
    float sv0 = 0.f, sv1 = 0.f;
    unsigned km0 = 0xFFFFFFFFu, km1 = 0xFFFFFFFFu;

    f32x16 acc0, acc1;                   // rt = 0 / 1
#pragma unroll
    for (int r = 0; r < 16; ++r) { acc0[r] = 0.f; acc1[r] = 0.f; }

    // per-wave B base: g-group = chalf*64 + cc*8 + wc; lane*8 is the linear fragment offset
    const unsigned char* gBcc = B8f + (size_t)(chalf * 64 + wc) * 16384 + lane * 8;
    int lane8 = lane * 8;
    int wlc = wc * 32 + 4 * kh;          // lane's col base within a cc (local)

    long bC0, bC1, bC2, bC3;             // current 4 B-fragments (named: no arrays, no spill)
    bC0 = *(const long*)(gBcc);
    bC1 = *(const long*)(gBcc + 512);
    bC2 = *(const long*)(gBcc + 1024);
    bC3 = *(const long*)(gBcc + 1536);

    for (int cc = 0; cc < 8; ++cc) {
#pragma unroll
        for (int kt = 0; kt < 8; ++kt) {
            long bN0, bN1, bN2, bN3;
            if (kt < 7) {                // prefetch next k-step of this cc
                const unsigned char* pn = gBcc + (kt + 1) * 2048;
                bN0 = *(const long*)(pn);
                bN1 = *(const long*)(pn + 512);
                bN2 = *(const long*)(pn + 1024);
                bN3 = *(const long*)(pn + 1536);
            } else if (cc < 7) {         // prefetch first k-step of next cc
                const unsigned char* pn = gBcc + 8 * 16384;
                bN0 = *(const long*)(pn);
                bN1 = *(const long*)(pn + 512);
                bN2 = *(const long*)(pn + 1024);
                bN3 = *(const long*)(pn + 1536);
            }
#pragma unroll
            for (int ksl = 0; ksl < 4; ++ksl) {
                const int m = kt * 4 + ksl;
                int ao = m * 512 + (lane8 ^ (m * 8));
                long aF0 = *(const long*)((const char*)aL + ao);
                long aF1 = *(const long*)((const char*)aL + 16384 + ao);
                long bFv = (ksl == 0) ? bC0 : (ksl == 1) ? bC1 : (ksl == 2) ? bC2 : bC3;
                acc0 = __builtin_amdgcn_mfma_f32_32x32x16_fp8_fp8(bFv, aF0, acc0, 0, 0, 0);
                acc1 = __builtin_amdgcn_mfma_f32_32x32x16_fp8_fp8(bFv, aF1, acc1, 0, 0, 0);
            }
            if (kt < 7 || cc < 7) { bC0 = bN0; bC1 = bN1; bC2 = bN2; bC3 = bN3; }
        }
        gBcc += 8 * 16384;
        // ---- epilogue burst for this cc (waves de-phase naturally: no barriers) ----
        int lc0 = cc * 256 + wlc;
#pragma unroll
        for (int r = 0; r < 16; ++r) {
            int lc = lc0 + (r & 3) + 8 * (r >> 2);
            float cbn = cbL[lc];
            float d0 = sqrtf(fmaxf(fmaf(-2.f, acc0[r], xn0) + cbn, 0.f));
            sv0 += __expf(dt0 - d0);
            km0 = min(km0, (__float_as_uint(d0) & 0xFFFFF000u) | (unsigned)(cbase + lc));
            float d1 = sqrtf(fmaxf(fmaf(-2.f, acc1[r], xn1) + cbn, 0.f));
            sv1 += __expf(dt1 - d1);
            km1 = min(km1, (__float_as_uint(d1) & 0xFFFFF000u) | (unsigned)(cbase + lc));
            acc0[r] = 0.f; acc1[r] = 0.f;
        }
    }

    // merge k-halves (lane vs lane+32: same student rows, disjoint cb-col quads)
    sv0 += __shfl_xor(sv0, 32);
    sv1 += __shfl_xor(sv1, 32);
    km0 = min(km0, (unsigned)__shfl_xor((int)km0, 32));
    km1 = min(km1, (unsigned)__shfl_xor((int)km1, 32));
    if (lane < 32) {
        atomicAdd(&s_sum[myrow0], sv0);
        atomicMin(&minpack[myrow0], km0);
        atomicAdd(&s_sum[myrow1], sv1);
        atomicMin(&minpack[myrow1], km1);
    }
}

// ---------------- Kernel 3a: per-token CE/accuracy/emb-loss/target-dist reduce ----------------
__global__ __launch_bounds__(256) void k3a(
    const float* __restrict__ s_sum,
    const unsigned* __restrict__ minpack,
    const int* __restrict__ codes,
    const float* __restrict__ dtg2,
    float* __restrict__ accum)
{
    __shared__ float w0[4], w1[4], w2[4], w3[4];
    int tid = threadIdx.x;
    int n = blockIdx.x * 256 + tid;
    float ce = logf(s_sum[n]);           // = d_t + lse(-d) = per-token CE
    unsigned pred = minpack[n] & 0xFFFu; // col id in the low 12 bits
    float ok = (pred == (unsigned)codes[n]) ? 1.f : 0.f;
    float sq = dtg2[n];
    float td = sqrtf(sq);
#pragma unroll
    for (int m = 1; m < 64; m <<= 1) {
        ce += __shfl_xor(ce, m);
        ok += __shfl_xor(ok, m);
        sq += __shfl_xor(sq, m);
        td += __shfl_xor(td, m);
    }
    int lane = tid & 63, w = tid >> 6;
    if (lane == 0) { w0[w] = ce; w1[w] = ok; w2[w] = sq; w3[w] = td; }
    __syncthreads();
    if (tid == 0) {
        atomicAdd(&accum[0], w0[0] + w0[1] + w0[2] + w0[3]);
        atomicAdd(&accum[1], w1[0] + w1[1] + w1[2] + w1[3]);
        atomicAdd(&accum[2], w2[0] + w2[1] + w2[2] + w2[3]);
        atomicAdd(&accum[3], w3[0] + w3[1] + w3[2] + w3[3]);
    }
}

// ---------------- Kernel 3b: finalize 5 outputs ----------------
__global__ void k3b(const float* __restrict__ accum, float* __restrict__ out)
{
    if (threadIdx.x == 0 && blockIdx.x == 0) {
        float ce   = accum[0] / (float)N_TOK;
        float accy = accum[1] / (float)N_TOK;
        float emb  = accum[2] / ((float)N_TOK * (float)C_);
        float td   = accum[3] / (float)N_TOK;
        out[0] = emb + ce;   // total_loss (EMB_W=CE_W=1)
        out[1] = emb;        // emb_to_codebook_loss
        out[2] = ce;         // ce_loss
        out[3] = accy;       // token_accuracy
        out[4] = td;         // emb_to_target_dist
    }
}

extern "C" void kernel_launch(void* const* d_in, const int* in_sizes, int n_in,
                              void* d_out, int out_size, void* d_ws, size_t ws_size,
                              hipStream_t stream)
{
    const float* student  = (const float*)d_in[0];
    const int*   codes    = (const int*)d_in[1];
    const float* codebook = (const float*)d_in[2];
    // d_in[3] distance_matrix is unused by the reference.
    float* out = (float*)d_out;

    char* ws = (char*)d_ws;
    unsigned char* A8     = (unsigned char*)(ws);                  // 8 MiB
    unsigned char* B8f    = (unsigned char*)(ws + 8388608);        // 2 MiB (fragment-linear)
    float* xnorm          = (float*)(ws + 10485760);               // 64 KiB
    float* dtg2           = (float*)(ws + 10551296);               // 64 KiB
    float* cbnorm         = (float*)(ws + 10616832);               // 16 KiB
    float* s_sum          = (float*)(ws + 10633216);               // 64 KiB
    unsigned* minpack     = (unsigned*)(ws + 10698752);            // 64 KiB
    float* accum          = (float*)(ws + 10829824);               // 64 B

    // k1_cb zero-inits s_sum/minpack/xnorm/dtg2/accum (stream-ordered before k1_prep's atomics)
    hipLaunchKernelGGL(k1_cb, dim3(1024), dim3(256), 0, stream,
                       codebook, B8f, cbnorm, s_sum, minpack, xnorm, dtg2, accum);
    hipLaunchKernelGGL(k1_prep, dim3(512), dim3(256), 0, stream,
                       student, codes, codebook, A8, xnorm, dtg2);
    hipLaunchKernelGGL(k2_main, dim3(512), dim3(512), 0, stream,
                       A8, B8f, xnorm, dtg2, cbnorm, s_sum, minpack);
    hipLaunchKernelGGL(k3a, dim3(64), dim3(256), 0, stream,
                       s_sum, minpack, codes, dtg2, accum);
    hipLaunchKernelGGL(k3b, dim3(1), dim3(64), 0, stream, accum, out);
}

// Round 14
// 129.355 us; speedup vs baseline: 1.4352x; 1.3023x over previous
//
#include <hip/hip_runtime.h>
#include <hip/hip_fp8.h>

#define C_ 512
#define T_ 2048
#define N_TOK 16384
#define K_CB 4096

typedef __attribute__((ext_vector_type(16))) float f32x16;
typedef __attribute__((ext_vector_type(2))) long long2v;

static __device__ __forceinline__ unsigned char f2fp8(float f) {
    __hip_fp8_e4m3 v(f);                 // OCP e4m3, RNE + saturate
    return (unsigned char)v.__x;
}

typedef const __attribute__((address_space(1))) void* gas_t;
typedef __attribute__((address_space(3))) void* las_t;
static __device__ __forceinline__ void stage16(const void* g, void* l) {
    __builtin_amdgcn_global_load_lds((gas_t)g, (las_t)l, 16, 0, 0);
}

// ---------------- Kernel 1: transpose student (B,C,T)->(N,C) fp8 + per-token partial stats ------
__global__ __launch_bounds__(256) void k1_prep(
    const float* __restrict__ student,   // (B,C,T) fp32
    const int* __restrict__ codes,       // (B,T) int32
    const float* __restrict__ codebook,  // (K,C) fp32
    unsigned char* __restrict__ A8,      // (N,C) fp8 out
    float* __restrict__ xnorm, float* __restrict__ dtg2)
{
    __shared__ float tile[64][65];
    __shared__ int lcodes[64];
    int tid = threadIdx.x;
    int tnum  = blockIdx.x >> 1;
    int chalf = blockIdx.x & 1;
    int b  = tnum >> 5;
    int t0 = (tnum & 31) << 6;
    int cbase = chalf << 8;             // 0 or 256
    int cx = tid & 63;                  // lane
    int q  = tid >> 6;                  // wave
    if (tid < 64) lcodes[tid] = codes[b * T_ + t0 + tid];
    __syncthreads();
    float ax2[16], ad2[16];
#pragma unroll
    for (int p = 0; p < 16; ++p) { ax2[p] = 0.f; ad2[p] = 0.f; }
    for (int c0 = cbase; c0 < cbase + 256; c0 += 64) {
#pragma unroll
        for (int p = 0; p < 16; ++p) {
            int ch = p * 4 + q;
            tile[ch][cx] = student[(size_t)b * (C_ * T_) + (size_t)(c0 + ch) * T_ + t0 + cx];
        }
        __syncthreads();
#pragma unroll
        for (int p = 0; p < 16; ++p) {
            int ty = p * 4 + q;
            float x = tile[cx][ty];
            int n = b * T_ + t0 + ty;
            A8[(size_t)n * C_ + c0 + cx] = f2fp8(x);
            ax2[p] += x * x;
            float cb = codebook[(size_t)lcodes[ty] * C_ + c0 + cx];
            float d = x - cb;
            ad2[p] += d * d;
        }
        __syncthreads();
    }
#pragma unroll
    for (int p = 0; p < 16; ++p) {
        float sx = ax2[p], sd = ad2[p];
#pragma unroll
        for (int m = 1; m < 64; m <<= 1) {
            sx += __shfl_xor(sx, m);
            sd += __shfl_xor(sd, m);
        }
        if (cx == 0) {
            int n = b * T_ + t0 + p * 4 + q;
            atomicAdd(&xnorm[n], sx);
            atomicAdd(&dtg2[n], sd);
        }
    }
}

// ---------------- Kernel 1b: codebook -> FRAGMENT-LINEAR fp8 + norms + init ----------------
// B8f layout: [g=row>>5][m=k>>4][kh][col=row&31][8B] -> wave B-fragment load is lane-linear:
// addr = g*16384 + m*512 + kh*256 + col*8 (512B contiguous per fragment).
__global__ __launch_bounds__(256) void k1_cb(
    const float* __restrict__ codebook,
    unsigned char* __restrict__ B8f,
    float* __restrict__ cbnorm,
    float* __restrict__ s_sum,
    unsigned* __restrict__ minpack,
    float* __restrict__ xnorm, float* __restrict__ dtg2,
    float* __restrict__ accum)
{
    int tid = threadIdx.x;
    int gidx = blockIdx.x * 256 + tid;
    if (gidx < N_TOK) {
        s_sum[gidx] = 0.f; minpack[gidx] = 0xFFFFFFFFu;
        xnorm[gidx] = 0.f; dtg2[gidx] = 0.f;
    }
    if (gidx < 8) accum[gidx] = 0.f;
    int lane = tid & 63;
    int w = tid >> 6;
    int row = blockIdx.x * 4 + w;
    const float* src = codebook + (size_t)row * C_ + lane * 8;
    float4 v0 = *(const float4*)(src);
    float4 v1 = *(const float4*)(src + 4);
    float s = v0.x*v0.x + v0.y*v0.y + v0.z*v0.z + v0.w*v0.w
            + v1.x*v1.x + v1.y*v1.y + v1.z*v1.z + v1.w*v1.w;
    unsigned lo = (unsigned)f2fp8(v0.x) | ((unsigned)f2fp8(v0.y) << 8)
                | ((unsigned)f2fp8(v0.z) << 16) | ((unsigned)f2fp8(v0.w) << 24);
    unsigned hi = (unsigned)f2fp8(v1.x) | ((unsigned)f2fp8(v1.y) << 8)
                | ((unsigned)f2fp8(v1.z) << 16) | ((unsigned)f2fp8(v1.w) << 24);
    // this lane's 8B = k-bytes [lane*8, lane*8+8) -> m = lane>>1, kh = lane&1
    size_t off = (size_t)(row >> 5) * 16384 + (size_t)(lane >> 1) * 512
               + (size_t)(lane & 1) * 256 + (size_t)(row & 31) * 8;
    *(uint2*)(B8f + off) = make_uint2(lo, hi);
#pragma unroll
    for (int m = 1; m < 64; m <<= 1) s += __shfl_xor(s, m);
    if (lane == 0) cbnorm[row] = s;
}

// ---------------- Kernel 2: barrier-free fp8 32x32 MFMA, m-pair fraglin-A LDS + streamed B ------
// grid = 512 (256 row-strips x 2 col-halves, XCD-chunked); block = 512 (8 waves, 1x8:
// wave = all 64 student rows x its own 32 cb-cols per cc).
// A LDS layout: [rt][j=m>>1][lane=kh*32+col][16B = frag(m=2j) | frag(m=2j+1)].
// Loop reads ds_read_b128 at lane*16 + imm(rt*16384 + j*1024): ONE addr reg, zero XOR VALU,
// conflict-free. B streamed from fragment-linear global (2 x b64 per j, L2-resident).
// One barrier total; no prefetch temporaries (arch-VGPR diet: stay under the 64-reg cap).
__global__ __launch_bounds__(512, 4) void k2_main(
    const unsigned char* __restrict__ A8,
    const unsigned char* __restrict__ B8f,
    const float* __restrict__ xnorm,
    const float* __restrict__ dtg2,
    const float* __restrict__ cbnorm,
    float* __restrict__ s_sum,
    unsigned* __restrict__ minpack)
{
    __shared__ __align__(16) unsigned char aL[32768];      // A: [rt2][j16][lane64][16B]
    __shared__ __align__(16) float cbL[2048];              // cbnorm for this col-half
    int tid = threadIdx.x;
    int lane = tid & 63;
    int wc = tid >> 6;                   // 0..7: wave owns cols [wc*32, wc*32+32) of each cc
    int l31 = lane & 31;
    int kh = lane >> 5;

    int orig = blockIdx.x;               // 512 = 8 XCD x 64
    int swz = (orig & 7) * 64 + (orig >> 3);
    int strip = swz >> 1;                // 0..255
    int chalf = swz & 1;
    int row0 = strip * 64;
    int cbase = chalf * 2048;

    // ---- stage A once, reg->LDS, m-pair fragment-linear layout ----
    // granule (R,M): 16B = A[row0+R][16M..16M+16). kh0-half -> lane (R&31), kh1 -> lane 32+(R&31),
    // within the 16B read-slot of j=M>>1 at byte (M&1)*8.
#pragma unroll
    for (int i = 0; i < 4; ++i) {
        int li = i * 512 + tid;
        int R = li >> 5, M = li & 31;
        uint4 v = *(const uint4*)(A8 + (size_t)(row0 + R) * C_ + M * 16);
        char* base = (char*)aL + (R >> 5) * 16384 + (M >> 1) * 1024 + (M & 1) * 8;
        *(uint2*)(base + (R & 31) * 16)       = make_uint2(v.x, v.y);   // kh = 0
        *(uint2*)(base + 512 + (R & 31) * 16) = make_uint2(v.z, v.w);   // kh = 1
    }
    // ---- stage cbnorm half once ----
    stage16((const char*)cbnorm + (size_t)cbase * 4 + tid * 16, (char*)cbL + tid * 16);
    __syncthreads();                     // the ONLY barrier

    int myrow0 = row0 + l31, myrow1 = row0 + 32 + l31;
    float xn0 = xnorm[myrow0], xn1 = xnorm[myrow1];
    float dt0 = sqrtf(dtg2[myrow0]), dt1 = sqrtf(dtg2[myrow1]);
    float sv0 = 0.f, sv1 = 0.f;
    unsigned km0 = 0xFFFFFFFFu, km1 = 0xFFFFFFFFu;

    f32x16 acc0, acc1;                   // rt = 0 / 1 (AGPRs)
#pragma unroll
    for (int r = 0; r < 16; ++r) { acc0[r] = 0.f; acc1[r] = 0.f; }

    const char* aBase = (const char*)aL + lane * 16;   // single addr reg; rest is imm offsets
    const unsigned char* gB = B8f + (size_t)(chalf * 64 + wc) * 16384 + lane * 8;
    int wlc = wc * 32 + 4 * kh;          // lane's col base within a cc (local)

    for (int cc = 0; cc < 8; ++cc) {
#pragma unroll 4
        for (int j = 0; j < 16; ++j) {
            long bE = *(const long*)(gB + j * 1024);          // B frag m=2j
            long bO = *(const long*)(gB + j * 1024 + 512);    // B frag m=2j+1
            long2v a0 = *(const long2v*)(aBase + j * 1024);           // rt0: {m=2j, m=2j+1}
            long2v a1 = *(const long2v*)(aBase + 16384 + j * 1024);   // rt1
            acc0 = __builtin_amdgcn_mfma_f32_32x32x16_fp8_fp8(bE, a0[0], acc0, 0, 0, 0);
            acc1 = __builtin_amdgcn_mfma_f32_32x32x16_fp8_fp8(bE, a1[0], acc1, 0, 0, 0);
            acc0 = __builtin_amdgcn_mfma_f32_32x32x16_fp8_fp8(bO, a0[1], acc0, 0, 0, 0);
            acc1 = __builtin_amdgcn_mfma_f32_32x32x16_fp8_fp8(bO, a1[1], acc1, 0, 0, 0);
        }
        gB += 8 * 16384;                 // next cc's g-group
        // ---- epilogue burst for this cc (waves de-phase naturally: no barriers) ----
        int lc0 = cc * 256 + wlc;
#pragma unroll
        for (int r = 0; r < 16; ++r) {
            int lc = lc0 + (r & 3) + 8 * (r >> 2);
            float cbn = cbL[lc];
            float d0 = sqrtf(fmaxf(fmaf(-2.f, acc0[r], xn0) + cbn, 0.f));
            sv0 += __expf(dt0 - d0);
            km0 = min(km0, (__float_as_uint(d0) & 0xFFFFF000u) | (unsigned)(cbase + lc));
            float d1 = sqrtf(fmaxf(fmaf(-2.f, acc1[r], xn1) + cbn, 0.f));
            sv1 += __expf(dt1 - d1);
            km1 = min(km1, (__float_as_uint(d1) & 0xFFFFF000u) | (unsigned)(cbase + lc));
            acc0[r] = 0.f; acc1[r] = 0.f;
        }
    }

    // merge k-halves (lane vs lane+32: same student rows, disjoint cb-col quads)
    sv0 += __shfl_xor(sv0, 32);
    sv1 += __shfl_xor(sv1, 32);
    km0 = min(km0, (unsigned)__shfl_xor((int)km0, 32));
    km1 = min(km1, (unsigned)__shfl_xor((int)km1, 32));
    if (lane < 32) {
        atomicAdd(&s_sum[myrow0], sv0);
        atomicMin(&minpack[myrow0], km0);
        atomicAdd(&s_sum[myrow1], sv1);
        atomicMin(&minpack[myrow1], km1);
    }
}

// ---------------- Kernel 3a: per-token CE/accuracy/emb-loss/target-dist reduce ----------------
__global__ __launch_bounds__(256) void k3a(
    const float* __restrict__ s_sum,
    const unsigned* __restrict__ minpack,
    const int* __restrict__ codes,
    const float* __restrict__ dtg2,
    float* __restrict__ accum)
{
    __shared__ float w0[4], w1[4], w2[4], w3[4];
    int tid = threadIdx.x;
    int n = blockIdx.x * 256 + tid;
    float ce = logf(s_sum[n]);           // = d_t + lse(-d) = per-token CE
    unsigned pred = minpack[n] & 0xFFFu; // col id in the low 12 bits
    float ok = (pred == (unsigned)codes[n]) ? 1.f : 0.f;
    float sq = dtg2[n];
    float td = sqrtf(sq);
#pragma unroll
    for (int m = 1; m < 64; m <<= 1) {
        ce += __shfl_xor(ce, m);
        ok += __shfl_xor(ok, m);
        sq += __shfl_xor(sq, m);
        td += __shfl_xor(td, m);
    }
    int lane = tid & 63, w = tid >> 6;
    if (lane == 0) { w0[w] = ce; w1[w] = ok; w2[w] = sq; w3[w] = td; }
    __syncthreads();
    if (tid == 0) {
        atomicAdd(&accum[0], w0[0] + w0[1] + w0[2] + w0[3]);
        atomicAdd(&accum[1], w1[0] + w1[1] + w1[2] + w1[3]);
        atomicAdd(&accum[2], w2[0] + w2[1] + w2[2] + w2[3]);
        atomicAdd(&accum[3], w3[0] + w3[1] + w3[2] + w3[3]);
    }
}

// ---------------- Kernel 3b: finalize 5 outputs ----------------
__global__ void k3b(const float* __restrict__ accum, float* __restrict__ out)
{
    if (threadIdx.x == 0 && blockIdx.x == 0) {
        float ce   = accum[0] / (float)N_TOK;
        float accy = accum[1] / (float)N_TOK;
        float emb  = accum[2] / ((float)N_TOK * (float)C_);
        float td   = accum[3] / (float)N_TOK;
        out[0] = emb + ce;   // total_loss (EMB_W=CE_W=1)
        out[1] = emb;        // emb_to_codebook_loss
        out[2] = ce;         // ce_loss
        out[3] = accy;       // token_accuracy
        out[4] = td;         // emb_to_target_dist
    }
}

extern "C" void kernel_launch(void* const* d_in, const int* in_sizes, int n_in,
                              void* d_out, int out_size, void* d_ws, size_t ws_size,
                              hipStream_t stream)
{
    const float* student  = (const float*)d_in[0];
    const int*   codes    = (const int*)d_in[1];
    const float* codebook = (const float*)d_in[2];
    // d_in[3] distance_matrix is unused by the reference.
    float* out = (float*)d_out;

    char* ws = (char*)d_ws;
    unsigned char* A8     = (unsigned char*)(ws);                  // 8 MiB
    unsigned char* B8f    = (unsigned char*)(ws + 8388608);        // 2 MiB (fragment-linear)
    float* xnorm          = (float*)(ws + 10485760);               // 64 KiB
    float* dtg2           = (float*)(ws + 10551296);               // 64 KiB
    float* cbnorm         = (float*)(ws + 10616832);               // 16 KiB
    float* s_sum          = (float*)(ws + 10633216);               // 64 KiB
    unsigned* minpack     = (unsigned*)(ws + 10698752);            // 64 KiB
    float* accum          = (float*)(ws + 10829824);               // 64 B

    // k1_cb zero-inits s_sum/minpack/xnorm/dtg2/accum (stream-ordered before k1_prep's atomics)
    hipLaunchKernelGGL(k1_cb, dim3(1024), dim3(256), 0, stream,
                       codebook, B8f, cbnorm, s_sum, minpack, xnorm, dtg2, accum);
    hipLaunchKernelGGL(k1_prep, dim3(512), dim3(256), 0, stream,
                       student, codes, codebook, A8, xnorm, dtg2);
    hipLaunchKernelGGL(k2_main, dim3(512), dim3(512), 0, stream,
                       A8, B8f, xnorm, dtg2, cbnorm, s_sum, minpack);
    hipLaunchKernelGGL(k3a, dim3(64), dim3(256), 0, stream,
                       s_sum, minpack, codes, dtg2, accum);
    hipLaunchKernelGGL(k3b, dim3(1), dim3(64), 0, stream, accum, out);
}

// Round 15
// 117.831 us; speedup vs baseline: 1.5756x; 1.0978x over previous
//
#include <hip/hip_runtime.h>
#include <hip/hip_fp8.h>

#define C_ 512
#define T_ 2048
#define N_TOK 16384
#define K_CB 4096

typedef __attribute__((ext_vector_type(16))) float f32x16;
typedef __attribute__((ext_vector_type(2))) long long2v;

static __device__ __forceinline__ unsigned char f2fp8(float f) {
    __hip_fp8_e4m3 v(f);                 // OCP e4m3, RNE + saturate
    return (unsigned char)v.__x;
}

static __device__ __forceinline__ float fsqrt(float x) {
#if __has_builtin(__builtin_amdgcn_sqrtf)
    return __builtin_amdgcn_sqrtf(x);    // raw v_sqrt_f32 (1-2 ulp), no Newton fixup
#else
    float r; asm volatile("v_sqrt_f32 %0, %1" : "=v"(r) : "v"(x)); return r;
#endif
}

typedef const __attribute__((address_space(1))) void* gas_t;
typedef __attribute__((address_space(3))) void* las_t;
static __device__ __forceinline__ void stage16(const void* g, void* l) {
    __builtin_amdgcn_global_load_lds((gas_t)g, (las_t)l, 16, 0, 0);
}

// ---------------- Kernel 1 (merged): blocks 0-511 = student transpose/stats; 512-1535 = codebook
// Init of xnorm/dtg2/s_sum/accum/minpack is done by hipMemsetAsync before this kernel.
__global__ __launch_bounds__(256) void k1_all(
    const float* __restrict__ student,   // (B,C,T) fp32
    const int* __restrict__ codes,       // (B,T) int32
    const float* __restrict__ codebook,  // (K,C) fp32
    unsigned char* __restrict__ A8,      // (N,C) fp8 out
    unsigned char* __restrict__ B8f,     // fragment-linear fp8 codebook out
    float* __restrict__ cbnorm,
    float* __restrict__ xnorm, float* __restrict__ dtg2)
{
    int tid = threadIdx.x;
    if (blockIdx.x >= 512) {
        // ---------------- codebook -> fragment-linear fp8 + row norms ----------------
        int lane = tid & 63;
        int w = tid >> 6;
        int row = (blockIdx.x - 512) * 4 + w;
        const float* src = codebook + (size_t)row * C_ + lane * 8;
        float4 v0 = *(const float4*)(src);
        float4 v1 = *(const float4*)(src + 4);
        float s = v0.x*v0.x + v0.y*v0.y + v0.z*v0.z + v0.w*v0.w
                + v1.x*v1.x + v1.y*v1.y + v1.z*v1.z + v1.w*v1.w;
        unsigned lo = (unsigned)f2fp8(v0.x) | ((unsigned)f2fp8(v0.y) << 8)
                    | ((unsigned)f2fp8(v0.z) << 16) | ((unsigned)f2fp8(v0.w) << 24);
        unsigned hi = (unsigned)f2fp8(v1.x) | ((unsigned)f2fp8(v1.y) << 8)
                    | ((unsigned)f2fp8(v1.z) << 16) | ((unsigned)f2fp8(v1.w) << 24);
        // lane's 8B = k-bytes [lane*8, lane*8+8) -> m = lane>>1, kh = lane&1
        size_t off = (size_t)(row >> 5) * 16384 + (size_t)(lane >> 1) * 512
                   + (size_t)(lane & 1) * 256 + (size_t)(row & 31) * 8;
        *(uint2*)(B8f + off) = make_uint2(lo, hi);
#pragma unroll
        for (int m = 1; m < 64; m <<= 1) s += __shfl_xor(s, m);
        if (lane == 0) cbnorm[row] = s;
        return;
    }
    // ---------------- student transpose (B,C,T)->(N,C) fp8 + per-token partial stats ----------
    __shared__ float tile[64][65];
    __shared__ int lcodes[64];
    int tnum  = blockIdx.x >> 1;
    int chalf = blockIdx.x & 1;
    int b  = tnum >> 5;
    int t0 = (tnum & 31) << 6;
    int cbase = chalf << 8;             // 0 or 256
    int cx = tid & 63;                  // lane
    int q  = tid >> 6;                  // wave
    if (tid < 64) lcodes[tid] = codes[b * T_ + t0 + tid];
    __syncthreads();
    float ax2[16], ad2[16];
#pragma unroll
    for (int p = 0; p < 16; ++p) { ax2[p] = 0.f; ad2[p] = 0.f; }
    for (int c0 = cbase; c0 < cbase + 256; c0 += 64) {
#pragma unroll
        for (int p = 0; p < 16; ++p) {
            int ch = p * 4 + q;
            tile[ch][cx] = student[(size_t)b * (C_ * T_) + (size_t)(c0 + ch) * T_ + t0 + cx];
        }
        __syncthreads();
#pragma unroll
        for (int p = 0; p < 16; ++p) {
            int ty = p * 4 + q;
            float x = tile[cx][ty];
            int n = b * T_ + t0 + ty;
            A8[(size_t)n * C_ + c0 + cx] = f2fp8(x);
            ax2[p] += x * x;
            float cb = codebook[(size_t)lcodes[ty] * C_ + c0 + cx];
            float d = x - cb;
            ad2[p] += d * d;
        }
        __syncthreads();
    }
#pragma unroll
    for (int p = 0; p < 16; ++p) {
        float sx = ax2[p], sd = ad2[p];
#pragma unroll
        for (int m = 1; m < 64; m <<= 1) {
            sx += __shfl_xor(sx, m);
            sd += __shfl_xor(sd, m);
        }
        if (cx == 0) {
            int n = b * T_ + t0 + p * 4 + q;
            atomicAdd(&xnorm[n], sx);
            atomicAdd(&dtg2[n], sd);
        }
    }
}

// ---------------- Kernel 2: barrier-free fp8 32x32 MFMA, m-pair fraglin-A LDS + streamed B ------
// (R14 structure, verified: VGPR 40, no spill, conflicts ~0)
// Epilogue: fast HW sqrt + d2-keyed argmin (sqrt off the min dep-chain).
__global__ __launch_bounds__(512, 4) void k2_main(
    const unsigned char* __restrict__ A8,
    const unsigned char* __restrict__ B8f,
    const float* __restrict__ xnorm,
    const float* __restrict__ dtg2,
    const float* __restrict__ cbnorm,
    float* __restrict__ s_sum,
    unsigned* __restrict__ minpack)
{
    __shared__ __align__(16) unsigned char aL[32768];      // A: [rt2][j16][lane64][16B]
    __shared__ __align__(16) float cbL[2048];              // cbnorm for this col-half
    int tid = threadIdx.x;
    int lane = tid & 63;
    int wc = tid >> 6;                   // 0..7: wave owns cols [wc*32, wc*32+32) of each cc
    int l31 = lane & 31;
    int kh = lane >> 5;

    int orig = blockIdx.x;               // 512 = 8 XCD x 64
    int swz = (orig & 7) * 64 + (orig >> 3);
    int strip = swz >> 1;                // 0..255
    int chalf = swz & 1;
    int row0 = strip * 64;
    int cbase = chalf * 2048;

    // ---- stage A once, reg->LDS, m-pair fragment-linear layout (R14-verified) ----
#pragma unroll
    for (int i = 0; i < 4; ++i) {
        int li = i * 512 + tid;
        int R = li >> 5, M = li & 31;
        uint4 v = *(const uint4*)(A8 + (size_t)(row0 + R) * C_ + M * 16);
        char* base = (char*)aL + (R >> 5) * 16384 + (M >> 1) * 1024 + (M & 1) * 8;
        *(uint2*)(base + (R & 31) * 16)       = make_uint2(v.x, v.y);   // kh = 0
        *(uint2*)(base + 512 + (R & 31) * 16) = make_uint2(v.z, v.w);   // kh = 1
    }
    // ---- stage cbnorm half once ----
    stage16((const char*)cbnorm + (size_t)cbase * 4 + tid * 16, (char*)cbL + tid * 16);
    __syncthreads();                     // the ONLY barrier

    int myrow0 = row0 + l31, myrow1 = row0 + 32 + l31;
    float xn0 = xnorm[myrow0], xn1 = xnorm[myrow1];
    float dt0 = fsqrt(dtg2[myrow0]), dt1 = fsqrt(dtg2[myrow1]);
    float sv0 = 0.f, sv1 = 0.f;
    unsigned km0 = 0xFFFFFFFFu, km1 = 0xFFFFFFFFu;

    f32x16 acc0, acc1;                   // rt = 0 / 1 (AGPRs)
#pragma unroll
    for (int r = 0; r < 16; ++r) { acc0[r] = 0.f; acc1[r] = 0.f; }

    const char* aBase = (const char*)aL + lane * 16;   // single addr reg; rest is imm offsets
    const unsigned char* gB = B8f + (size_t)(chalf * 64 + wc) * 16384 + lane * 8;
    int wlc = wc * 32 + 4 * kh;          // lane's col base within a cc (local)

    for (int cc = 0; cc < 8; ++cc) {
#pragma unroll 4
        for (int j = 0; j < 16; ++j) {
            long bE = *(const long*)(gB + j * 1024);          // B frag m=2j
            long bO = *(const long*)(gB + j * 1024 + 512);    // B frag m=2j+1
            long2v a0 = *(const long2v*)(aBase + j * 1024);           // rt0: {m=2j, m=2j+1}
            long2v a1 = *(const long2v*)(aBase + 16384 + j * 1024);   // rt1
            acc0 = __builtin_amdgcn_mfma_f32_32x32x16_fp8_fp8(bE, a0[0], acc0, 0, 0, 0);
            acc1 = __builtin_amdgcn_mfma_f32_32x32x16_fp8_fp8(bE, a1[0], acc1, 0, 0, 0);
            acc0 = __builtin_amdgcn_mfma_f32_32x32x16_fp8_fp8(bO, a0[1], acc0, 0, 0, 0);
            acc1 = __builtin_amdgcn_mfma_f32_32x32x16_fp8_fp8(bO, a1[1], acc1, 0, 0, 0);
        }
        gB += 8 * 16384;                 // next cc's g-group
        // ---- epilogue burst: fast sqrt; argmin keyed on d2 bits (monotonic == same argmin) ----
        int lc0 = cc * 256 + wlc;
#pragma unroll
        for (int r = 0; r < 16; ++r) {
            int lc = lc0 + (r & 3) + 8 * (r >> 2);
            float cbn = cbL[lc];
            float d2a = fmaxf(fmaf(-2.f, acc0[r], xn0) + cbn, 0.f);
            sv0 += __expf(dt0 - fsqrt(d2a));
            km0 = min(km0, (__float_as_uint(d2a) & 0xFFFFF000u) | (unsigned)(cbase + lc));
            float d2b = fmaxf(fmaf(-2.f, acc1[r], xn1) + cbn, 0.f);
            sv1 += __expf(dt1 - fsqrt(d2b));
            km1 = min(km1, (__float_as_uint(d2b) & 0xFFFFF000u) | (unsigned)(cbase + lc));
            acc0[r] = 0.f; acc1[r] = 0.f;
        }
    }

    // merge k-halves (lane vs lane+32: same student rows, disjoint cb-col quads)
    sv0 += __shfl_xor(sv0, 32);
    sv1 += __shfl_xor(sv1, 32);
    km0 = min(km0, (unsigned)__shfl_xor((int)km0, 32));
    km1 = min(km1, (unsigned)__shfl_xor((int)km1, 32));
    if (lane < 32) {
        atomicAdd(&s_sum[myrow0], sv0);
        atomicMin(&minpack[myrow0], km0);
        atomicAdd(&s_sum[myrow1], sv1);
        atomicMin(&minpack[myrow1], km1);
    }
}

// ---------------- Kernel 3a: per-token CE/accuracy/emb-loss/target-dist reduce ----------------
__global__ __launch_bounds__(256) void k3a(
    const float* __restrict__ s_sum,
    const unsigned* __restrict__ minpack,
    const int* __restrict__ codes,
    const float* __restrict__ dtg2,
    float* __restrict__ accum)
{
    __shared__ float w0[4], w1[4], w2[4], w3[4];
    int tid = threadIdx.x;
    int n = blockIdx.x * 256 + tid;
    float ce = logf(s_sum[n]);           // = d_t + lse(-d) = per-token CE
    unsigned pred = minpack[n] & 0xFFFu; // col id in the low 12 bits
    float ok = (pred == (unsigned)codes[n]) ? 1.f : 0.f;
    float sq = dtg2[n];
    float td = sqrtf(sq);
#pragma unroll
    for (int m = 1; m < 64; m <<= 1) {
        ce += __shfl_xor(ce, m);
        ok += __shfl_xor(ok, m);
        sq += __shfl_xor(sq, m);
        td += __shfl_xor(td, m);
    }
    int lane = tid & 63, w = tid >> 6;
    if (lane == 0) { w0[w] = ce; w1[w] = ok; w2[w] = sq; w3[w] = td; }
    __syncthreads();
    if (tid == 0) {
        atomicAdd(&accum[0], w0[0] + w0[1] + w0[2] + w0[3]);
        atomicAdd(&accum[1], w1[0] + w1[1] + w1[2] + w1[3]);
        atomicAdd(&accum[2], w2[0] + w2[1] + w2[2] + w2[3]);
        atomicAdd(&accum[3], w3[0] + w3[1] + w3[2] + w3[3]);
    }
}

// ---------------- Kernel 3b: finalize 5 outputs ----------------
__global__ void k3b(const float* __restrict__ accum, float* __restrict__ out)
{
    if (threadIdx.x == 0 && blockIdx.x == 0) {
        float ce   = accum[0] / (float)N_TOK;
        float accy = accum[1] / (float)N_TOK;
        float emb  = accum[2] / ((float)N_TOK * (float)C_);
        float td   = accum[3] / (float)N_TOK;
        out[0] = emb + ce;   // total_loss (EMB_W=CE_W=1)
        out[1] = emb;        // emb_to_codebook_loss
        out[2] = ce;         // ce_loss
        out[3] = accy;       // token_accuracy
        out[4] = td;         // emb_to_target_dist
    }
}

extern "C" void kernel_launch(void* const* d_in, const int* in_sizes, int n_in,
                              void* d_out, int out_size, void* d_ws, size_t ws_size,
                              hipStream_t stream)
{
    const float* student  = (const float*)d_in[0];
    const int*   codes    = (const int*)d_in[1];
    const float* codebook = (const float*)d_in[2];
    // d_in[3] distance_matrix is unused by the reference.
    float* out = (float*)d_out;

    char* ws = (char*)d_ws;
    unsigned char* A8     = (unsigned char*)(ws);                  // 8 MiB
    unsigned char* B8f    = (unsigned char*)(ws + 8388608);        // 2 MiB (fragment-linear)
    float* xnorm          = (float*)(ws + 10485760);               // 64 KiB  ─┐
    float* dtg2           = (float*)(ws + 10551296);               // 64 KiB   │ one zero-memset
    float* s_sum          = (float*)(ws + 10616832);               // 64 KiB   │
    float* accum          = (float*)(ws + 10682368);               // 64 B    ─┘
    unsigned* minpack     = (unsigned*)(ws + 10682624);            // 64 KiB (0xFF memset)
    float* cbnorm         = (float*)(ws + 10748160);               // 16 KiB (fully written by k1)

    hipMemsetAsync(ws + 10485760, 0, 196672, stream);              // xnorm+dtg2+s_sum+accum
    hipMemsetAsync(ws + 10682624, 0xFF, 65536, stream);            // minpack

    // merged prep: blocks 0-511 student transpose/stats, 512-1535 codebook conversion
    hipLaunchKernelGGL(k1_all, dim3(1536), dim3(256), 0, stream,
                       student, codes, codebook, A8, B8f, cbnorm, xnorm, dtg2);
    hipLaunchKernelGGL(k2_main, dim3(512), dim3(512), 0, stream,
                       A8, B8f, xnorm, dtg2, cbnorm, s_sum, minpack);
    hipLaunchKernelGGL(k3a, dim3(64), dim3(256), 0, stream,
                       s_sum, minpack, codes, dtg2, accum);
    hipLaunchKernelGGL(k3b, dim3(1), dim3(64), 0, stream, accum, out);
}

// Round 16
// 105.613 us; speedup vs baseline: 1.7579x; 1.1157x over previous
//
#include <hip/hip_runtime.h>
#include <hip/hip_fp8.h>

#define C_ 512
#define T_ 2048
#define N_TOK 16384
#define K_CB 4096

typedef __attribute__((ext_vector_type(16))) float f32x16;
typedef __attribute__((ext_vector_type(2))) long long2v;

static __device__ __forceinline__ unsigned char f2fp8(float f) {
    __hip_fp8_e4m3 v(f);                 // OCP e4m3, RNE + saturate
    return (unsigned char)v.__x;
}

static __device__ __forceinline__ float fsqrt(float x) {
#if __has_builtin(__builtin_amdgcn_sqrtf)
    return __builtin_amdgcn_sqrtf(x);    // raw v_sqrt_f32 (1-2 ulp), no Newton fixup
#else
    float r; asm volatile("v_sqrt_f32 %0, %1" : "=v"(r) : "v"(x)); return r;
#endif
}

typedef const __attribute__((address_space(1))) void* gas_t;
typedef __attribute__((address_space(3))) void* las_t;
static __device__ __forceinline__ void stage16(const void* g, void* l) {
    __builtin_amdgcn_global_load_lds((gas_t)g, (las_t)l, 16, 0, 0);
}

// ---------------- Kernel 1 (merged): blocks 0-511 = student transpose/stats; 512-1535 = codebook
// Student loads vectorized: float4 along T (1KB/wave/instr). Init by hipMemsetAsync.
__global__ __launch_bounds__(256) void k1_all(
    const float* __restrict__ student,   // (B,C,T) fp32
    const int* __restrict__ codes,       // (B,T) int32
    const float* __restrict__ codebook,  // (K,C) fp32
    unsigned char* __restrict__ A8,      // (N,C) fp8 out
    unsigned char* __restrict__ B8f,     // fragment-linear fp8 codebook out
    float* __restrict__ cbnorm,
    float* __restrict__ xnorm, float* __restrict__ dtg2)
{
    int tid = threadIdx.x;
    if (blockIdx.x >= 512) {
        // ---------------- codebook -> fragment-linear fp8 + row norms ----------------
        int lane = tid & 63;
        int w = tid >> 6;
        int row = (blockIdx.x - 512) * 4 + w;
        const float* src = codebook + (size_t)row * C_ + lane * 8;
        float4 v0 = *(const float4*)(src);
        float4 v1 = *(const float4*)(src + 4);
        float s = v0.x*v0.x + v0.y*v0.y + v0.z*v0.z + v0.w*v0.w
                + v1.x*v1.x + v1.y*v1.y + v1.z*v1.z + v1.w*v1.w;
        unsigned lo = (unsigned)f2fp8(v0.x) | ((unsigned)f2fp8(v0.y) << 8)
                    | ((unsigned)f2fp8(v0.z) << 16) | ((unsigned)f2fp8(v0.w) << 24);
        unsigned hi = (unsigned)f2fp8(v1.x) | ((unsigned)f2fp8(v1.y) << 8)
                    | ((unsigned)f2fp8(v1.z) << 16) | ((unsigned)f2fp8(v1.w) << 24);
        // lane's 8B = k-bytes [lane*8, lane*8+8) -> m = lane>>1, kh = lane&1
        size_t off = (size_t)(row >> 5) * 16384 + (size_t)(lane >> 1) * 512
                   + (size_t)(lane & 1) * 256 + (size_t)(row & 31) * 8;
        *(uint2*)(B8f + off) = make_uint2(lo, hi);
#pragma unroll
        for (int m = 1; m < 64; m <<= 1) s += __shfl_xor(s, m);
        if (lane == 0) cbnorm[row] = s;
        return;
    }
    // ---------------- student transpose (B,C,T)->(N,C) fp8 + per-token partial stats ----------
    __shared__ float tile[64][65];
    __shared__ int lcodes[64];
    int tnum  = blockIdx.x >> 1;
    int chalf = blockIdx.x & 1;
    int b  = tnum >> 5;
    int t0 = (tnum & 31) << 6;
    int cbase = chalf << 8;             // 0 or 256
    int cx = tid & 63;                  // lane
    int q  = tid >> 6;                  // wave
    if (tid < 64) lcodes[tid] = codes[b * T_ + t0 + tid];
    __syncthreads();
    float ax2[16], ad2[16];
#pragma unroll
    for (int p = 0; p < 16; ++p) { ax2[p] = 0.f; ad2[p] = 0.f; }
    for (int c0 = cbase; c0 < cbase + 256; c0 += 64) {
        // vectorized tile fill: wave q covers channels [q*16, q*16+16), float4 along T
#pragma unroll
        for (int i = 0; i < 4; ++i) {
            int ch = q * 16 + i * 4 + (cx >> 4);
            int tq = cx & 15;
            float4 v = *(const float4*)(student + (size_t)b * (C_ * T_)
                                        + (size_t)(c0 + ch) * T_ + t0 + tq * 4);
            tile[ch][tq * 4 + 0] = v.x;
            tile[ch][tq * 4 + 1] = v.y;
            tile[ch][tq * 4 + 2] = v.z;
            tile[ch][tq * 4 + 3] = v.w;
        }
        __syncthreads();
#pragma unroll
        for (int p = 0; p < 16; ++p) {
            int ty = p * 4 + q;
            float x = tile[cx][ty];
            int n = b * T_ + t0 + ty;
            A8[(size_t)n * C_ + c0 + cx] = f2fp8(x);
            ax2[p] += x * x;
            float cb = codebook[(size_t)lcodes[ty] * C_ + c0 + cx];
            float d = x - cb;
            ad2[p] += d * d;
        }
        __syncthreads();
    }
#pragma unroll
    for (int p = 0; p < 16; ++p) {
        float sx = ax2[p], sd = ad2[p];
#pragma unroll
        for (int m = 1; m < 64; m <<= 1) {
            sx += __shfl_xor(sx, m);
            sd += __shfl_xor(sd, m);
        }
        if (cx == 0) {
            int n = b * T_ + t0 + p * 4 + q;
            atomicAdd(&xnorm[n], sx);
            atomicAdd(&dtg2[n], sd);
        }
    }
}

// ---------------- Kernel 2: barrier-free fp8 32x32 MFMA, m-pair fraglin-A LDS + streamed B ------
// grid = 1024 (256 row-strips x 4 col-QUARTERS, XCD-chunked); block = 512 (8 waves, 1x8:
// wave = all 64 student rows x its own 32 cb-cols per cc; cc = 4 chunks of 256 cols).
// LDS = 36,864B/WG -> 4 WG/CU (147KB of 160KB), 32 waves/CU: TLP covers VALU bursts.
// A LDS: [rt][j=m>>1][lane][16B] m-pair fraglin (R14-verified, conflict-free, 1 addr reg).
// B streamed from fragment-linear global (coalesced, L2-resident). One barrier total.
__global__ __launch_bounds__(512, 4) void k2_main(
    const unsigned char* __restrict__ A8,
    const unsigned char* __restrict__ B8f,
    const float* __restrict__ xnorm,
    const float* __restrict__ dtg2,
    const float* __restrict__ cbnorm,
    float* __restrict__ s_sum,
    unsigned* __restrict__ minpack)
{
    __shared__ __align__(16) unsigned char aL[32768];      // A: [rt2][j16][lane64][16B]
    __shared__ __align__(16) float cbL[1024];              // cbnorm for this col-quarter
    int tid = threadIdx.x;
    int lane = tid & 63;
    int wc = tid >> 6;                   // 0..7: wave owns cols [wc*32, wc*32+32) of each cc
    int l31 = lane & 31;
    int kh = lane >> 5;

    int orig = blockIdx.x;               // 1024 = 8 XCD x 128
    int swz = (orig & 7) * 128 + (orig >> 3);
    int strip = swz >> 2;                // 0..255
    int cq = swz & 3;                    // col quarter 0..3
    int row0 = strip * 64;
    int cbase = cq * 1024;

    // ---- stage A once, reg->LDS, m-pair fragment-linear layout (R14-verified) ----
#pragma unroll
    for (int i = 0; i < 4; ++i) {
        int li = i * 512 + tid;
        int R = li >> 5, M = li & 31;
        uint4 v = *(const uint4*)(A8 + (size_t)(row0 + R) * C_ + M * 16);
        char* base = (char*)aL + (R >> 5) * 16384 + (M >> 1) * 1024 + (M & 1) * 8;
        *(uint2*)(base + (R & 31) * 16)       = make_uint2(v.x, v.y);   // kh = 0
        *(uint2*)(base + 512 + (R & 31) * 16) = make_uint2(v.z, v.w);   // kh = 1
    }
    // ---- stage cbnorm quarter once (1024 floats = 256 granules) ----
    if (tid < 256)
        stage16((const char*)cbnorm + (size_t)cbase * 4 + tid * 16, (char*)cbL + tid * 16);
    __syncthreads();                     // the ONLY barrier

    int myrow0 = row0 + l31, myrow1 = row0 + 32 + l31;
    float xn0 = xnorm[myrow0], xn1 = xnorm[myrow1];
    float dt0 = fsqrt(dtg2[myrow0]), dt1 = fsqrt(dtg2[myrow1]);
    float sv0 = 0.f, sv1 = 0.f;
    unsigned km0 = 0xFFFFFFFFu, km1 = 0xFFFFFFFFu;

    f32x16 acc0, acc1;                   // rt = 0 / 1 (AGPRs)
#pragma unroll
    for (int r = 0; r < 16; ++r) { acc0[r] = 0.f; acc1[r] = 0.f; }

    const char* aBase = (const char*)aL + lane * 16;   // single addr reg; rest is imm offsets
    const unsigned char* gB = B8f + (size_t)(cq * 32 + wc) * 16384 + lane * 8;
    int wlc = wc * 32 + 4 * kh;          // lane's col base within a cc (local)

    for (int cc = 0; cc < 4; ++cc) {
#pragma unroll 4
        for (int j = 0; j < 16; ++j) {
            long bE = *(const long*)(gB + j * 1024);          // B frag m=2j
            long bO = *(const long*)(gB + j * 1024 + 512);    // B frag m=2j+1
            long2v a0 = *(const long2v*)(aBase + j * 1024);           // rt0: {m=2j, m=2j+1}
            long2v a1 = *(const long2v*)(aBase + 16384 + j * 1024);   // rt1
            acc0 = __builtin_amdgcn_mfma_f32_32x32x16_fp8_fp8(bE, a0[0], acc0, 0, 0, 0);
            acc1 = __builtin_amdgcn_mfma_f32_32x32x16_fp8_fp8(bE, a1[0], acc1, 0, 0, 0);
            acc0 = __builtin_amdgcn_mfma_f32_32x32x16_fp8_fp8(bO, a0[1], acc0, 0, 0, 0);
            acc1 = __builtin_amdgcn_mfma_f32_32x32x16_fp8_fp8(bO, a1[1], acc1, 0, 0, 0);
        }
        gB += 8 * 16384;                 // next cc's g-group
        // ---- epilogue burst: fast sqrt; argmin keyed on d2 bits (monotonic == same argmin) ----
        int lc0 = cc * 256 + wlc;
#pragma unroll
        for (int r = 0; r < 16; ++r) {
            int lc = lc0 + (r & 3) + 8 * (r >> 2);
            float cbn = cbL[lc];
            float d2a = fmaxf(fmaf(-2.f, acc0[r], xn0) + cbn, 0.f);
            sv0 += __expf(dt0 - fsqrt(d2a));
            km0 = min(km0, (__float_as_uint(d2a) & 0xFFFFF000u) | (unsigned)(cbase + lc));
            float d2b = fmaxf(fmaf(-2.f, acc1[r], xn1) + cbn, 0.f);
            sv1 += __expf(dt1 - fsqrt(d2b));
            km1 = min(km1, (__float_as_uint(d2b) & 0xFFFFF000u) | (unsigned)(cbase + lc));
            acc0[r] = 0.f; acc1[r] = 0.f;
        }
    }

    // merge k-halves (lane vs lane+32: same student rows, disjoint cb-col quads)
    sv0 += __shfl_xor(sv0, 32);
    sv1 += __shfl_xor(sv1, 32);
    km0 = min(km0, (unsigned)__shfl_xor((int)km0, 32));
    km1 = min(km1, (unsigned)__shfl_xor((int)km1, 32));
    if (lane < 32) {
        atomicAdd(&s_sum[myrow0], sv0);
        atomicMin(&minpack[myrow0], km0);
        atomicAdd(&s_sum[myrow1], sv1);
        atomicMin(&minpack[myrow1], km1);
    }
}

// ---------------- Kernel 3a: per-token CE/accuracy/emb-loss/target-dist reduce ----------------
__global__ __launch_bounds__(256) void k3a(
    const float* __restrict__ s_sum,
    const unsigned* __restrict__ minpack,
    const int* __restrict__ codes,
    const float* __restrict__ dtg2,
    float* __restrict__ accum)
{
    __shared__ float w0[4], w1[4], w2[4], w3[4];
    int tid = threadIdx.x;
    int n = blockIdx.x * 256 + tid;
    float ce = logf(s_sum[n]);           // = d_t + lse(-d) = per-token CE
    unsigned pred = minpack[n] & 0xFFFu; // col id in the low 12 bits
    float ok = (pred == (unsigned)codes[n]) ? 1.f : 0.f;
    float sq = dtg2[n];
    float td = sqrtf(sq);
#pragma unroll
    for (int m = 1; m < 64; m <<= 1) {
        ce += __shfl_xor(ce, m);
        ok += __shfl_xor(ok, m);
        sq += __shfl_xor(sq, m);
        td += __shfl_xor(td, m);
    }
    int lane = tid & 63, w = tid >> 6;
    if (lane == 0) { w0[w] = ce; w1[w] = ok; w2[w] = sq; w3[w] = td; }
    __syncthreads();
    if (tid == 0) {
        atomicAdd(&accum[0], w0[0] + w0[1] + w0[2] + w0[3]);
        atomicAdd(&accum[1], w1[0] + w1[1] + w1[2] + w1[3]);
        atomicAdd(&accum[2], w2[0] + w2[1] + w2[2] + w2[3]);
        atomicAdd(&accum[3], w3[0] + w3[1] + w3[2] + w3[3]);
    }
}

// ---------------- Kernel 3b: finalize 5 outputs ----------------
__global__ void k3b(const float* __restrict__ accum, float* __restrict__ out)
{
    if (threadIdx.x == 0 && blockIdx.x == 0) {
        float ce   = accum[0] / (float)N_TOK;
        float accy = accum[1] / (float)N_TOK;
        float emb  = accum[2] / ((float)N_TOK * (float)C_);
        float td   = accum[3] / (float)N_TOK;
        out[0] = emb + ce;   // total_loss (EMB_W=CE_W=1)
        out[1] = emb;        // emb_to_codebook_loss
        out[2] = ce;         // ce_loss
        out[3] = accy;       // token_accuracy
        out[4] = td;         // emb_to_target_dist
    }
}

extern "C" void kernel_launch(void* const* d_in, const int* in_sizes, int n_in,
                              void* d_out, int out_size, void* d_ws, size_t ws_size,
                              hipStream_t stream)
{
    const float* student  = (const float*)d_in[0];
    const int*   codes    = (const int*)d_in[1];
    const float* codebook = (const float*)d_in[2];
    // d_in[3] distance_matrix is unused by the reference.
    float* out = (float*)d_out;

    char* ws = (char*)d_ws;
    unsigned char* A8     = (unsigned char*)(ws);                  // 8 MiB
    unsigned char* B8f    = (unsigned char*)(ws + 8388608);        // 2 MiB (fragment-linear)
    float* xnorm          = (float*)(ws + 10485760);               // 64 KiB  ─┐
    float* dtg2           = (float*)(ws + 10551296);               // 64 KiB   │ one zero-memset
    float* s_sum          = (float*)(ws + 10616832);               // 64 KiB   │
    float* accum          = (float*)(ws + 10682368);               // 64 B    ─┘
    unsigned* minpack     = (unsigned*)(ws + 10682624);            // 64 KiB (0xFF memset)
    float* cbnorm         = (float*)(ws + 10748160);               // 16 KiB (fully written by k1)

    hipMemsetAsync(ws + 10485760, 0, 196672, stream);              // xnorm+dtg2+s_sum+accum
    hipMemsetAsync(ws + 10682624, 0xFF, 65536, stream);            // minpack

    // merged prep: blocks 0-511 student transpose/stats, 512-1535 codebook conversion
    hipLaunchKernelGGL(k1_all, dim3(1536), dim3(256), 0, stream,
                       student, codes, codebook, A8, B8f, cbnorm, xnorm, dtg2);
    hipLaunchKernelGGL(k2_main, dim3(1024), dim3(512), 0, stream,
                       A8, B8f, xnorm, dtg2, cbnorm, s_sum, minpack);
    hipLaunchKernelGGL(k3a, dim3(64), dim3(256), 0, stream,
                       s_sum, minpack, codes, dtg2, accum);
    hipLaunchKernelGGL(k3b, dim3(1), dim3(64), 0, stream, accum, out);
}